// Round 1
// baseline (183.724 us; speedup 1.0000x reference)
//
#include <hip/hip_runtime.h>

#define HIDDEN 1024
#define NTOK (8 * 2048)   // B*S = 16384 tokens
#define BM 128
#define BN 128
#define BK 32

typedef __attribute__((ext_vector_type(4))) float f32x4;
typedef __attribute__((ext_vector_type(8))) short bf16x8;
typedef __attribute__((ext_vector_type(4))) unsigned short u16x4;
typedef __attribute__((ext_vector_type(8))) unsigned short u16x8;

typedef __attribute__((address_space(3))) unsigned int lds_u32;
typedef __attribute__((address_space(1))) unsigned int glb_u32;

__device__ inline unsigned short f2b(float f) {
    unsigned int u = __float_as_uint(f);
    u += 0x7fffu + ((u >> 16) & 1u);   // round-to-nearest-even
    return (unsigned short)(u >> 16);
}
__device__ inline float b2f(unsigned short u) {
    return __uint_as_float(((unsigned int)u) << 16);
}

// ---------------- fp32 -> bf16 convert (vectorized, grid-stride) -------------
__global__ __launch_bounds__(256) void cvt_f2b(const float4* __restrict__ in,
                                               u16x4* __restrict__ out, int n4) {
    int stride = gridDim.x * blockDim.x;
    for (int i = blockIdx.x * blockDim.x + threadIdx.x; i < n4; i += stride) {
        float4 x = in[i];
        u16x4 r;
        r[0] = f2b(x.x); r[1] = f2b(x.y); r[2] = f2b(x.z); r[3] = f2b(x.w);
        out[i] = r;
    }
}

// ---------------- fused QKV GEMM: C = X (16384x1024) * W^T + bias ------------
// grid.x = NTOK/BM row-blocks, grid.y = 24 col-blocks (8 per matrix; q,k,v)
__global__ __launch_bounds__(256) void qkv_gemm(
    const unsigned short* __restrict__ Xb,
    const unsigned short* __restrict__ Wb,
    const float* __restrict__ bq, const float* __restrict__ bk,
    const float* __restrict__ bv,
    unsigned short* __restrict__ QKV) {
    __shared__ __align__(16) unsigned short As[BM * BK];
    __shared__ __align__(16) unsigned short Bs[BN * BK];

    const int t = threadIdx.x;
    const int lane = t & 63, wave = t >> 6;
    const int wm = wave >> 1, wn = wave & 1;       // 2x2 wave grid, 64x64 each
    const int cb = blockIdx.y;
    const int mat = cb >> 3;                       // 0=q 1=k 2=v
    const int col0 = (cb & 7) * BN;
    const int row0 = blockIdx.x * BM;

    const unsigned short* W = Wb + (size_t)mat * (HIDDEN * HIDDEN);
    const float* bias = (mat == 0) ? bq : ((mat == 1) ? bk : bv);
    unsigned short* Out = QKV + (size_t)mat * ((size_t)NTOK * HIDDEN);

    f32x4 acc[4][4] = {};

    const int srow = lane >> 2;          // row within 16-row chunk
    const int scol = (lane & 3) * 8;     // element offset within row

    for (int kb = 0; kb < HIDDEN; kb += BK) {
        __syncthreads();                 // prior compute done before overwrite
#pragma unroll
        for (int i = 0; i < 2; ++i) {
            const int c = i * 4 + wave;              // 16-row chunk index, wave-uniform
            const int r = c * 16 + srow;
            const unsigned short* gA = Xb + (size_t)(row0 + r) * HIDDEN + kb + scol;
            const unsigned short* gB = W  + (size_t)(col0 + r) * HIDDEN + kb + scol;
            __builtin_amdgcn_global_load_lds((const glb_u32*)gA,
                                             (lds_u32*)(As + c * 16 * BK), 16, 0, 0);
            __builtin_amdgcn_global_load_lds((const glb_u32*)gB,
                                             (lds_u32*)(Bs + c * 16 * BK), 16, 0, 0);
        }
        __syncthreads();                 // staging complete (vmcnt drained)

        const int fr = lane & 15;
        const int k0 = (lane >> 4) * 8;
        bf16x8 a[4], b[4];
#pragma unroll
        for (int m = 0; m < 4; ++m)
            a[m] = *(const bf16x8*)(As + (wm * 64 + m * 16 + fr) * BK + k0);
#pragma unroll
        for (int n = 0; n < 4; ++n)
            b[n] = *(const bf16x8*)(Bs + (wn * 64 + n * 16 + fr) * BK + k0);
#pragma unroll
        for (int m = 0; m < 4; ++m)
#pragma unroll
            for (int n = 0; n < 4; ++n)
                acc[m][n] = __builtin_amdgcn_mfma_f32_16x16x32_bf16(
                    a[m], b[n], acc[m][n], 0, 0, 0);
    }

    // epilogue: bias add, bf16 store.  C/D map: col=lane&15, row=(lane>>4)*4+reg
    const int fr = lane & 15;
    const int fq = lane >> 4;
#pragma unroll
    for (int m = 0; m < 4; ++m) {
#pragma unroll
        for (int n = 0; n < 4; ++n) {
            const int colg = col0 + wn * 64 + n * 16 + fr;
            const float bsv = bias[colg];
#pragma unroll
            for (int j = 0; j < 4; ++j) {
                const int rowg = row0 + wm * 64 + m * 16 + fq * 4 + j;
                Out[(size_t)rowg * HIDDEN + colg] = f2b(acc[m][n][j] + bsv);
            }
        }
    }
}

// ---------------- per-token attention over the HEAD dim ----------------------
// one wave per token; lane = h*8+g computes score[h][g]; softmax over g.
__global__ __launch_bounds__(256) void attn_k(const unsigned short* __restrict__ QKV,
                                              float* __restrict__ out) {
    __shared__ unsigned short sQ[4][HIDDEN];
    __shared__ unsigned short sK[4][HIDDEN];
    __shared__ unsigned short sV[4][HIDDEN];
    __shared__ float sA[4][64];

    const int t = threadIdx.x, lane = t & 63, wave = t >> 6;
    const int token = blockIdx.x * 4 + wave;
    const size_t base = (size_t)token * HIDDEN;
    const unsigned short* q = QKV + base;
    const unsigned short* k = QKV + (size_t)NTOK * HIDDEN + base;
    const unsigned short* v = QKV + 2 * (size_t)NTOK * HIDDEN + base;

#pragma unroll
    for (int i = 0; i < 2; ++i) {
        const int off = (i * 64 + lane) * 8;
        *(u16x8*)&sQ[wave][off] = *(const u16x8*)&q[off];
        *(u16x8*)&sK[wave][off] = *(const u16x8*)&k[off];
        *(u16x8*)&sV[wave][off] = *(const u16x8*)&v[off];
    }
    __syncthreads();

    const int h = lane >> 3, g = lane & 7;
    float sc = 0.f;
    const unsigned short* Qr = &sQ[wave][h * 128];
    const unsigned short* Kr = &sK[wave][g * 128];
#pragma unroll
    for (int d = 0; d < 128; d += 8) {
        u16x8 qv = *(const u16x8*)&Qr[d];
        u16x8 kv = *(const u16x8*)&Kr[d];
#pragma unroll
        for (int j = 0; j < 8; ++j) sc += b2f(qv[j]) * b2f(kv[j]);
    }
    sc *= -0.08838834764831845f;   // NEGATED scale, faithful to source quirk

    float mx = sc;
#pragma unroll
    for (int o = 1; o < 8; o <<= 1) mx = fmaxf(mx, __shfl_xor(mx, o, 64));
    const float e = __expf(sc - mx);
    float sm = e;
#pragma unroll
    for (int o = 1; o < 8; o <<= 1) sm += __shfl_xor(sm, o, 64);
    sA[wave][lane] = e / sm;
    __syncthreads();

    const int c = lane & 7;        // 16-wide d-chunk within head
    float ov[16];
#pragma unroll
    for (int j = 0; j < 16; ++j) ov[j] = 0.f;
    const float* Ar = &sA[wave][h * 8];
#pragma unroll
    for (int gg = 0; gg < 8; ++gg) {
        const float a = Ar[gg];
        const unsigned short* Vr = &sV[wave][gg * 128 + c * 16];
#pragma unroll
        for (int j = 0; j < 16; ++j) ov[j] += a * b2f(Vr[j]);
    }
    float* op = out + base + lane * 16;   // lane*16 == h*128 + c*16
#pragma unroll
    for (int j = 0; j < 16; j += 4) {
        float4 r = make_float4(ov[j], ov[j + 1], ov[j + 2], ov[j + 3]);
        *(float4*)&op[j] = r;
    }
}

extern "C" void kernel_launch(void* const* d_in, const int* in_sizes, int n_in,
                              void* d_out, int out_size, void* d_ws, size_t ws_size,
                              hipStream_t stream) {
    const float* x1 = (const float*)d_in[0];
    const float* Wq = (const float*)d_in[1];
    const float* bq = (const float*)d_in[2];
    const float* Wk = (const float*)d_in[3];
    const float* bk = (const float*)d_in[4];
    const float* Wv = (const float*)d_in[5];
    const float* bv = (const float*)d_in[6];
    float* out = (float*)d_out;

    // workspace layout (bf16 as ushort): Xb | Wb(q,k,v) | QKV  -> 140.5 MB
    unsigned short* Xb  = (unsigned short*)d_ws;
    unsigned short* Wb  = Xb + (size_t)NTOK * HIDDEN;
    unsigned short* QKV = Wb + 3 * (size_t)HIDDEN * HIDDEN;

    cvt_f2b<<<2048, 256, 0, stream>>>((const float4*)x1, (u16x4*)Xb,
                                      NTOK * HIDDEN / 4);
    cvt_f2b<<<512, 256, 0, stream>>>((const float4*)Wq, (u16x4*)Wb,
                                     HIDDEN * HIDDEN / 4);
    cvt_f2b<<<512, 256, 0, stream>>>((const float4*)Wk,
                                     (u16x4*)(Wb + HIDDEN * HIDDEN),
                                     HIDDEN * HIDDEN / 4);
    cvt_f2b<<<512, 256, 0, stream>>>((const float4*)Wv,
                                     (u16x4*)(Wb + 2 * HIDDEN * HIDDEN),
                                     HIDDEN * HIDDEN / 4);

    dim3 grid(NTOK / BM, 24);
    qkv_gemm<<<grid, 256, 0, stream>>>(Xb, Wb, bq, bk, bv, QKV);

    attn_k<<<NTOK / 4, 256, 0, stream>>>(QKV, out);
}